// Round 14
// baseline (425.954 us; speedup 1.0000x reference)
//
#include <hip/hip_runtime.h>
#include <hip/hip_bf16.h>
#include <math.h>

#define L2E 1.44269504f
#define LN2 0.69314718f
#define TSTRIDE 68

typedef __attribute__((ext_vector_type(2))) float floatx2;

__device__ __forceinline__ float sigf(float x){ return 1.0f/(1.0f+expf(-x)); }

__device__ __forceinline__ float quad_max(float x) {
    x = fmaxf(x, __int_as_float(__builtin_amdgcn_mov_dpp(__float_as_int(x), 0xB1, 0xF, 0xF, true)));
    x = fmaxf(x, __int_as_float(__builtin_amdgcn_mov_dpp(__float_as_int(x), 0x4E, 0xF, 0xF, true)));
    return x;
}
// 8-lane reductions, pure DPP (xor1, xor2, half-row mirror)
__device__ __forceinline__ float oct_max(float x) {
    x = fmaxf(x, __int_as_float(__builtin_amdgcn_mov_dpp(__float_as_int(x), 0xB1, 0xF, 0xF, true)));
    x = fmaxf(x, __int_as_float(__builtin_amdgcn_mov_dpp(__float_as_int(x), 0x4E, 0xF, 0xF, true)));
    x = fmaxf(x, __int_as_float(__builtin_amdgcn_mov_dpp(__float_as_int(x), 0x141, 0xF, 0xF, true)));
    return x;
}
__device__ __forceinline__ float oct_sum(float x) {
    x += __int_as_float(__builtin_amdgcn_mov_dpp(__float_as_int(x), 0xB1, 0xF, 0xF, true));
    x += __int_as_float(__builtin_amdgcn_mov_dpp(__float_as_int(x), 0x4E, 0xF, 0xF, true));
    x += __int_as_float(__builtin_amdgcn_mov_dpp(__float_as_int(x), 0x141, 0xF, 0xF, true));
    return x;
}

// Grid barrier: monotonic counter, device-scope atomics (cross-XCD safe),
// threadfence = writeback before arrival / invalidate after release.
// 256 blocks <= 256 CUs, <=54KB LDS, launch_bounds(512,2) -> all co-resident.
__device__ __forceinline__ void gbar(unsigned* cnt, unsigned target) {
    __threadfence();
    __syncthreads();
    if (threadIdx.x == 0) {
        atomicAdd(cnt, 1u);
        while (atomicAdd(cnt, 0u) < target) __builtin_amdgcn_s_sleep(10);
    }
    __syncthreads();
    __threadfence();
}

// ---------------------------------------------------------------- prep: embed + bias + fp8 pack + barrier init
__global__ __launch_bounds__(256) void prep_all(const float* __restrict__ Whh_f, const float* __restrict__ Whh_b,
                             const float* __restrict__ bih_f, const float* __restrict__ bhh_f,
                             const float* __restrict__ bih_b, const float* __restrict__ bhh_b,
                             uint4* __restrict__ qWf, uint4* __restrict__ qWb,
                             float* __restrict__ scf, float* __restrict__ scb,
                             float* __restrict__ biasf, float* __restrict__ biasb,
                             const int* __restrict__ sents, const float* __restrict__ mask,
                             const float* __restrict__ emb, float* __restrict__ embeds,
                             float* __restrict__ out, unsigned* __restrict__ bar) {
    int tid = threadIdx.x;
    if (blockIdx.x < 512) {
        int bl = blockIdx.x;
        const int*   srow = sents + bl*32;
        const float* mrow = mask  + bl*32;
        float acc = 0.0f, el = 0.0f;
        for (int w = 0; w < 32; ++w) {
            float m = mrow[w];
            el  += m;
            acc += emb[(size_t)srow[w]*256 + tid] * m;
        }
        float den = el + (el == 0.0f ? 1.0f : 0.0f);
        embeds[bl*256 + tid] = acc / den;
        if (bl == 0)      { for (int q = tid; q < 1024; q += 256) biasf[q] = bih_f[q] + bhh_f[q]; }
        else if (bl == 1) { for (int q = tid; q < 1024; q += 256) biasb[q] = bih_b[q] + bhh_b[q]; }
        else if (bl == 2 && tid == 0) { out[0] = 0.0f; atomicExch(bar, 0u); }
    } else {
        int pb  = blockIdx.x - 512;      // 0..127
        int dir = pb >> 6;
        int cg  = pb & 63;               // cell group of 4
        const float* W = dir ? Whh_b : Whh_f;
        uint4* qW = dir ? qWb : qWf;
        float* sc = dir ? scb : scf;
        __shared__ float Wl[16][260];    // 16 rows (4 gates x 4 cells), padded
        __shared__ float sL[16];         // row scales [g*4+jj]
        #pragma unroll
        for (int lr = 0; lr < 16; ++lr) {
            int g = lr >> 2, jj = lr & 3;
            int rowid = g*256 + cg*4 + jj;
            Wl[lr][tid] = W[(size_t)rowid*256 + tid];
        }
        __syncthreads();
        if (tid < 64) {
            int lr = tid >> 2, sub = tid & 3;
            float mx = 0.0f;
            for (int m = 0; m < 64; ++m) mx = fmaxf(mx, fabsf(Wl[lr][sub*64 + m]));
            mx = quad_max(mx);
            if (sub == 0) sL[lr] = mx * (1.0f/240.0f) + 1e-30f;
        }
        __syncthreads();
        int k4 = tid >> 2, jj = tid & 3;
        float is0 = 1.0f / sL[0*4 + jj];
        float is1 = 1.0f / sL[1*4 + jj];
        float is2 = 1.0f / sL[2*4 + jj];
        float is3 = 1.0f / sL[3*4 + jj];
        uint4 q;
        unsigned int* qq = (unsigned int*)&q;
        #pragma unroll
        for (int kk = 0; kk < 4; ++kk) {
            int k = k4*4 + kk;
            int d = 0;
            d = __builtin_amdgcn_cvt_pk_fp8_f32(Wl[0*4+jj][k]*is0, Wl[1*4+jj][k]*is1, d, false);
            d = __builtin_amdgcn_cvt_pk_fp8_f32(Wl[2*4+jj][k]*is2, Wl[3*4+jj][k]*is3, d, true);
            qq[kk] = (unsigned int)d;
        }
        qW[k4*256 + cg*4 + jj] = q;
        if (tid < 16) {
            int g = tid >> 2, j2 = tid & 3;
            sc[(cg*4 + j2)*4 + g] = sL[g*4 + j2];
        }
    }
}

// ---------------------------------------------------------------- fused: gemm_ih -> lstm -> post -> eisner
// 256 blocks x 512 threads; 3 grid barriers replace 3 kernel launches.
__global__ __launch_bounds__(512, 2) void fused_main(
        const float* __restrict__ embeds,
        const float* __restrict__ Wih_f, const float* __restrict__ Wih_b,
        const float* __restrict__ biasf, const float* __restrict__ biasb,
        float* __restrict__ gxf, float* __restrict__ gxb,
        const uint4* __restrict__ qWf, const uint4* __restrict__ qWb,
        const float* __restrict__ scf, const float* __restrict__ scb,
        float* __restrict__ hall,
        const float* __restrict__ Ws, float* __restrict__ u, float* __restrict__ v,
        const float* __restrict__ W1, const float* __restrict__ b1,
        const float* __restrict__ W2, const float* __restrict__ b2,
        float* __restrict__ p1, float* __restrict__ p2,
        const float* __restrict__ bs, const float* __restrict__ prior,
        const int* __restrict__ heads,
        float* __restrict__ out, unsigned* __restrict__ bar) {
    __shared__ __align__(16) float SMEM[3*64*TSTRIDE + 64];
    __shared__ float su[64], sv[64], lseSb[64], sBest[1];
    __shared__ float ru2[2][4], rv2[2][4];
    int tid = threadIdx.x;
    int blk = blockIdx.x;

    // ================= F1: gemm_ih -- one 64x64 tile per block, 512 thr
    {
        int dir  = blk >> 7;
        int rest = blk & 127;
        int bx = rest >> 4, by = rest & 15;
        const float* A    = embeds;
        const float* Bm   = dir ? Wih_b : Wih_f;
        const float* bias = dir ? biasb : biasf;
        float* C          = dir ? gxb : gxf;
        const int N = 1024, K = 256;
        float* As = SMEM;              // [32][68]
        float* Bs = SMEM + 32*68;      // [32][68]
        int tx = tid & 15, ty = tid >> 4;        // ty 0..31 -> 2 rows each
        int row0 = bx * 64, col0 = by * 64;
        float acc[2][4];
        #pragma unroll
        for (int r = 0; r < 2; ++r)
            #pragma unroll
            for (int c = 0; c < 4; ++c) acc[r][c] = 0.0f;
        int lr = tid >> 3;             // 0..63
        int lc = (tid & 7) * 4;        // 0,4,..,28
        for (int k0 = 0; k0 < K; k0 += 32) {
            float4 a0 = *(const float4*)(A  + (size_t)(row0+lr)*K + k0 + lc);
            float4 b0 = *(const float4*)(Bm + (size_t)(col0+lr)*K + k0 + lc);
            As[(lc  )*68 + lr] = a0.x; As[(lc+1)*68 + lr] = a0.y;
            As[(lc+2)*68 + lr] = a0.z; As[(lc+3)*68 + lr] = a0.w;
            Bs[(lc  )*68 + lr] = b0.x; Bs[(lc+1)*68 + lr] = b0.y;
            Bs[(lc+2)*68 + lr] = b0.z; Bs[(lc+3)*68 + lr] = b0.w;
            __syncthreads();
            #pragma unroll
            for (int kc = 0; kc < 32; ++kc) {
                float2 xa = *(const float2*)&As[kc*68 + ty*2];
                float4 xb = *(const float4*)&Bs[kc*68 + tx*4];
                acc[0][0] = fmaf(xa.x, xb.x, acc[0][0]);
                acc[0][1] = fmaf(xa.x, xb.y, acc[0][1]);
                acc[0][2] = fmaf(xa.x, xb.z, acc[0][2]);
                acc[0][3] = fmaf(xa.x, xb.w, acc[0][3]);
                acc[1][0] = fmaf(xa.y, xb.x, acc[1][0]);
                acc[1][1] = fmaf(xa.y, xb.y, acc[1][1]);
                acc[1][2] = fmaf(xa.y, xb.z, acc[1][2]);
                acc[1][3] = fmaf(xa.y, xb.w, acc[1][3]);
            }
            __syncthreads();
        }
        float4 bv = *(const float4*)&bias[col0 + tx*4];
        #pragma unroll
        for (int r = 0; r < 2; ++r) {
            float4 o;
            o.x = acc[r][0] + bv.x; o.y = acc[r][1] + bv.y;
            o.z = acc[r][2] + bv.z; o.w = acc[r][3] + bv.w;
            *(float4*)(C + (size_t)(row0 + ty*2 + r)*N + col0 + tx*4) = o;
        }
    }
    gbar(bar, 256);

    // ================= F2: LSTM recurrence (2-way K split, 2 reps)
    {
        int lb   = blk;
        int rep  = lb >> 7;
        lb &= 127;
        int dir  = lb >> 6;
        int pos  = lb & 63;
        int j    = tid & 255;
        int half = tid >> 8;
        const float* gx = dir ? gxb : gxf;
        const uint4* qW = dir ? qWb : qWf;
        float4 sc = ((const float4*)(dir ? scb : scf))[j];
        float* hs = SMEM;                              // 256 floats
        float (*part)[4] = (float(*)[4])(SMEM + 256);  // 256x4 floats
        if (tid < 256) hs[tid] = 0.0f;
        float cellc = 0.0f;
        __syncthreads();
        const uint4* qWh = qW + (half << 13);
        const float* hsh = hs + (half << 7);
        for (int s = 0; s < 8; ++s) {
            int t = dir ? (7 - s) : s;
            const float* g0 = gx + (size_t)(t*64 + pos)*1024;
            float ai = 0.0f, af = 0.0f, ag = 0.0f, ao = 0.0f;
            if (half == 0) { ai = g0[j]; af = g0[256+j]; ag = g0[512+j]; ao = g0[768+j]; }
            float qi = 0.0f, qf = 0.0f, qg = 0.0f, qo = 0.0f;
            #pragma unroll 8
            for (int k4 = 0; k4 < 32; ++k4) {
                uint4 wq = qWh[(k4 << 8) + j];
                float4 hp = *(const float4*)&hsh[k4*4];
                floatx2 pa, pb;
                pa = __builtin_amdgcn_cvt_pk_f32_fp8(wq.x, false);
                pb = __builtin_amdgcn_cvt_pk_f32_fp8(wq.x, true);
                qi = fmaf(pa.x, hp.x, qi); qf = fmaf(pa.y, hp.x, qf);
                qg = fmaf(pb.x, hp.x, qg); qo = fmaf(pb.y, hp.x, qo);
                pa = __builtin_amdgcn_cvt_pk_f32_fp8(wq.y, false);
                pb = __builtin_amdgcn_cvt_pk_f32_fp8(wq.y, true);
                qi = fmaf(pa.x, hp.y, qi); qf = fmaf(pa.y, hp.y, qf);
                qg = fmaf(pb.x, hp.y, qg); qo = fmaf(pb.y, hp.y, qo);
                pa = __builtin_amdgcn_cvt_pk_f32_fp8(wq.z, false);
                pb = __builtin_amdgcn_cvt_pk_f32_fp8(wq.z, true);
                qi = fmaf(pa.x, hp.z, qi); qf = fmaf(pa.y, hp.z, qf);
                qg = fmaf(pb.x, hp.z, qg); qo = fmaf(pb.y, hp.z, qo);
                pa = __builtin_amdgcn_cvt_pk_f32_fp8(wq.w, false);
                pb = __builtin_amdgcn_cvt_pk_f32_fp8(wq.w, true);
                qi = fmaf(pa.x, hp.w, qi); qf = fmaf(pa.y, hp.w, qf);
                qg = fmaf(pb.x, hp.w, qg); qo = fmaf(pb.y, hp.w, qo);
            }
            if (half) { part[j][0] = qi; part[j][1] = qf; part[j][2] = qg; part[j][3] = qo; }
            __syncthreads();
            if (half == 0) {
                float4 pr = *(const float4*)&part[j][0];
                ai = fmaf(sc.x, qi + pr.x, ai);
                af = fmaf(sc.y, qf + pr.y, af);
                ag = fmaf(sc.z, qg + pr.z, ag);
                ao = fmaf(sc.w, qo + pr.w, ao);
                cellc = sigf(af)*cellc + sigf(ai)*tanhf(ag);
                float h0 = sigf(ao)*tanhf(cellc);
                hs[j] = h0;
                if (rep == 0) hall[(size_t)(t*64 + pos)*512 + dir*256 + j] = h0;
            }
            __syncthreads();
        }
    }
    gbar(bar, 512);

    // ================= F3: uv (blocks 128-255, 4 units each) / p1,p2 gemm32 (blocks 0-127)
    if (blk >= 128) {
        int h  = tid >> 8;        // half handles its own uv unit
        int t2 = tid & 255;
        for (int p = 0; p < 2; ++p) {
            int bi = (blk - 128)*4 + p*2 + h;      // 0..511
            int i  = bi & 63;
            float pu = 0.0f, pv = 0.0f;
            for (int q = t2; q < 1536; q += 256) {
                int seg = q >> 9, kk = q & 511;
                float tv = 0.0f;
                if (seg == 0)       tv = hall[(size_t)bi*512 + kk];
                else if (seg == 1)  { if (i > 0)  tv = hall[(size_t)(bi-1)*512 + kk]; }
                else                { if (i < 63) tv = hall[(size_t)(bi+1)*512 + kk]; }
                pu = fmaf(tv, Ws[q],        pu);
                pv = fmaf(tv, Ws[1536 + q], pv);
            }
            for (int off = 32; off; off >>= 1) { pu += __shfl_xor(pu, off); pv += __shfl_xor(pv, off); }
            int wv = t2 >> 6, lane = t2 & 63;
            if (lane == 0) { ru2[h][wv] = pu; rv2[h][wv] = pv; }
            __syncthreads();
            if (t2 == 0) {
                u[bi] = ru2[h][0]+ru2[h][1]+ru2[h][2]+ru2[h][3];
                v[bi] = rv2[h][0]+rv2[h][1]+rv2[h][2]+rv2[h][3];
            }
            __syncthreads();
        }
    } else {
        int sel = blk >> 6, un = blk & 63;         // 64 tiles per matrix
        const float* A    = hall;
        const float* Bm   = sel ? W2 : W1;
        const float* bias = sel ? b2 : b1;
        float* C          = sel ? p2 : p1;
        int bx = un >> 2, by = un & 3;
        const int N = 128, K = 512;
        float* As2 = SMEM;             // [32][36]
        float* Bs2 = SMEM + 32*36;
        int tx = tid & 15, ty = (tid >> 4) & 15;
        int row0 = bx * 32, col0 = by * 32;
        float a00 = 0.f, a01 = 0.f, a10 = 0.f, a11 = 0.f;
        int lr = (tid >> 3) & 31;
        int lc = (tid & 7) * 4;
        for (int k0 = 0; k0 < K; k0 += 32) {
            if (tid < 256) {
                float4 av = *(const float4*)(A  + (size_t)(row0+lr)*K + k0 + lc);
                float4 bv = *(const float4*)(Bm + (size_t)(col0+lr)*K + k0 + lc);
                As2[(lc  )*36 + lr] = av.x; As2[(lc+1)*36 + lr] = av.y;
                As2[(lc+2)*36 + lr] = av.z; As2[(lc+3)*36 + lr] = av.w;
                Bs2[(lc  )*36 + lr] = bv.x; Bs2[(lc+1)*36 + lr] = bv.y;
                Bs2[(lc+2)*36 + lr] = bv.z; Bs2[(lc+3)*36 + lr] = bv.w;
            }
            __syncthreads();
            if (tid < 256) {
                #pragma unroll
                for (int kc = 0; kc < 32; ++kc) {
                    float2 xa = *(const float2*)&As2[kc*36 + ty*2];
                    float2 xb = *(const float2*)&Bs2[kc*36 + tx*2];
                    a00 = fmaf(xa.x, xb.x, a00);
                    a01 = fmaf(xa.x, xb.y, a01);
                    a10 = fmaf(xa.y, xb.x, a10);
                    a11 = fmaf(xa.y, xb.y, a11);
                }
            }
            __syncthreads();
        }
        if (tid < 256) {
            float2 bv = *(const float2*)&bias[col0 + tx*2];
            float2 o0; o0.x = a00 + bv.x; o0.y = a01 + bv.y;
            float2 o1; o1.x = a10 + bv.x; o1.y = a11 + bv.y;
            *(float2*)(C + (size_t)(row0 + ty*2    )*N + col0 + tx*2) = o0;
            *(float2*)(C + (size_t)(row0 + ty*2 + 1)*N + col0 + tx*2) = o1;
        }
    }
    gbar(bar, 768);

    // ================= F4: Eisner (round-13 linear-domain body, verbatim)
    {
        int b   = blk & 7;
        int rep = blk >> 3;
        float* T1 = &SMEM[0];
        float* T2 = &SMEM[64*TSTRIDE];
        float* T3 = &SMEM[2*64*TSTRIDE];
        float bsv = bs[0];
        if (tid < 64) {
            su[tid] = u[b*64 + tid];
            sv[tid] = v[b*64 + tid];
        }
        const float4* g1 = (const float4*)(p1 + (size_t)b*8192);
        const float4* g2 = (const float4*)(p2 + (size_t)b*8192);
        float4* s1p = (float4*)SMEM;
        float4* s2p = (float4*)(SMEM + 64*TSTRIDE);
        int r   = tid >> 3;
        int sub = tid & 7;
        float acc[8];
        #pragma unroll
        for (int q = 0; q < 8; ++q) acc[q] = 0.0f;
        __syncthreads();     // all F3 LDS use done before restage
        for (int p = 0; p < 2; ++p) {
            #pragma unroll
            for (int f0 = 0; f0 < 4; ++f0) {
                int f = f0*512 + tid;
                int half = f >> 10;
                int ff = f & 1023;
                int row = ff >> 4, c4 = ff & 15;
                float4 vv = (half ? g2 : g1)[row*32 + (p<<4) + c4];
                (half ? s2p : s1p)[row*17 + c4] = vv;
            }
            __syncthreads();
            #pragma unroll 2
            for (int k4 = 0; k4 < 16; ++k4) {
                float4 a = s1p[r*17 + k4];
                #pragma unroll
                for (int q = 0; q < 8; ++q) {
                    float4 bv = s2p[(sub + (q<<3))*17 + k4];
                    acc[q] = fmaf(a.x, bv.x, acc[q]);
                    acc[q] = fmaf(a.y, bv.y, acc[q]);
                    acc[q] = fmaf(a.z, bv.z, acc[q]);
                    acc[q] = fmaf(a.w, bv.w, acc[q]);
                }
            }
            __syncthreads();
        }
        float pm = acc[0];
        #pragma unroll
        for (int q = 1; q < 8; ++q) pm = fmaxf(pm, acc[q]);
        pm = oct_max(pm);
        float ps = 0.0f;
        #pragma unroll
        for (int q = 0; q < 8; ++q) ps += exp2f((acc[q] - pm) * L2E);
        ps = oct_sum(ps);
        if (sub == 0) lseSb[r] = pm + log2f(ps) * LN2;
        float* Sl = SMEM;
        #pragma unroll
        for (int q = 0; q < 8; ++q) Sl[r*66 + sub + (q<<3)] = acc[q];
        __syncthreads();
        if (tid < 64) {
            int m = tid;
            float gv = -INFINITY;
            if (m >= 1) {
                int hd = heads[b*64 + m];
                gv = su[hd] + sv[m] + bsv + (Sl[hd*66 + m] - lseSb[hd])
                   + prior[(size_t)(b*64 + hd)*64 + m] * (1.0f/64.0f);
            }
            float mm = gv;
            for (int off = 32; off; off >>= 1) mm = fmaxf(mm, __shfl_xor(mm, off));
            float se = (m >= 1) ? exp2f((gv - mm) * L2E) : 0.0f;
            for (int off = 32; off; off >>= 1) se += __shfl_xor(se, off);
            if (m == 0) sBest[0] = mm + log2f(se) * LN2;
        }
        __syncthreads();
        for (int q = tid; q < 3*64*TSTRIDE; q += 512) SMEM[q] = 0.0f;
        __syncthreads();
        if (tid < 64) {
            T1[tid*TSTRIDE + tid] = 1.0f;
            if (tid >= 1) T2[tid*TSTRIDE + tid-1] = 1.0f;
        }
        __syncthreads();
        int i = r;
        int k0 = i & ~3;
        float sui_b = su[i] + bsv;
        float svi_b = sv[i] + bsv;
        const float* t1i = &T1[i*TSTRIDE];
        const float* t2i = &T2[i*TSTRIDE];
        const float* t3i = &T3[i*TSTRIDE];
        for (int w = 1; w < 64; ++w) {
            int ns = 64 - w;
            if (i < ns) {
                int j = i + w;
                const float* t1j = &T1[j*TSTRIDE];
                const float* t2j = &T2[j*TSTRIDE];
                const float* t3j = &T3[j*TSTRIDE];
                float eDr = exp2f((sui_b + sv[j]) * L2E);
                float eDl = exp2f((su[j] + svi_b) * L2E);
                float s1 = 0.0f, sr = 0.0f, sl = 0.0f;
                #pragma unroll
                for (int t = 0; t < 2; ++t) {
                    int k = k0 + ((t << 3) + sub) * 4;
                    if (k < j) {
                        float4 a1  = *(const float4*)&t1i[k];
                        float4 b1  = *(const float4*)&t2j[k];
                        float4 a2  = *(const float4*)&t3i[k];
                        float4 b2v = *(const float4*)&t1j[k];
                        float4 a3  = *(const float4*)&t2i[k];
                        float4 b3  = *(const float4*)&t3j[k];
                        #pragma unroll
                        for (int c = 0; c < 4; ++c) {
                            s1 = fmaf(((const float*)&a1)[c], ((const float*)&b1)[c],  s1);
                            sr = fmaf(((const float*)&a2)[c], ((const float*)&b2v)[c], sr);
                            sl = fmaf(((const float*)&a3)[c], ((const float*)&b3)[c],  sl);
                        }
                    }
                }
                s1 = oct_sum(s1);
                sr = oct_sum(sr);
                sl = oct_sum(sl);
                if (sub == 0) {
                    float Ir = 0.25f * s1 * eDr;
                    float Il = 0.25f * s1 * eDl;
                    float Cr = sr + Ir;
                    float Cl = sl + Il;
                    T3[i*TSTRIDE + j] = Ir;
                    T1[i*TSTRIDE + j] = Cr;
                    T1[j*TSTRIDE + i] = Cr;
                    T3[j*TSTRIDE + i] = Il;
                    T2[i*TSTRIDE + j] = Cl;
                    if (i >= 1) T2[j*TSTRIDE + i-1] = Cl;
                }
            }
            __syncthreads();
        }
        if (rep == 0 && tid == 0) {
            float logZv = (log2f(T1[0*TSTRIDE + 63]) + 126.0f) * LN2;
            atomicAdd(out, -(sBest[0] - logZv) * 0.125f);
        }
    }
}

// ---------------------------------------------------------------- launch
extern "C" void kernel_launch(void* const* d_in, const int* in_sizes, int n_in,
                              void* d_out, int out_size, void* d_ws, size_t ws_size,
                              hipStream_t stream) {
    const int*   sents = (const int*)  d_in[0];
    const float* mask  = (const float*)d_in[1];
    const float* prior = (const float*)d_in[2];
    const int*   heads = (const int*)  d_in[3];
    const float* emb   = (const float*)d_in[4];
    const float* Wih_f = (const float*)d_in[5];
    const float* Whh_f = (const float*)d_in[6];
    const float* bih_f = (const float*)d_in[7];
    const float* bhh_f = (const float*)d_in[8];
    const float* Wih_b = (const float*)d_in[9];
    const float* Whh_b = (const float*)d_in[10];
    const float* bih_b = (const float*)d_in[11];
    const float* bhh_b = (const float*)d_in[12];
    const float* W1    = (const float*)d_in[13];
    const float* b1    = (const float*)d_in[14];
    const float* W2    = (const float*)d_in[15];
    const float* b2    = (const float*)d_in[16];
    const float* Ws    = (const float*)d_in[17];
    const float* bs    = (const float*)d_in[18];
    float* out = (float*)d_out;

    char* w = (char*)d_ws;
    float* embeds = (float*)(w + 0);                 // 512 KB
    float* gxf    = (float*)(w + 524288);            // 2 MB
    float* gxb    = (float*)(w + 2621440);           // 2 MB
    uint4* qWf    = (uint4*)(w + 4718592);           // 256 KB
    uint4* qWb    = (uint4*)(w + 4980736);           // 256 KB
    float* scf    = (float*)(w + 5242880);           // 4 KB
    float* scb    = (float*)(w + 5246976);           // 4 KB
    float* biasf  = (float*)(w + 5767168);           // 4 KB
    float* biasb  = (float*)(w + 5771264);           // 4 KB
    float* hall   = (float*)(w + 5775360);           // 1 MB
    float* uArr   = (float*)(w + 6823936);
    float* vArr   = (float*)(w + 6825984);
    float* p1     = (float*)(w + 6828032);
    float* p2     = (float*)(w + 7090176);
    unsigned* bar = (unsigned*)(w + 7352320);        // grid-barrier counter

    prep_all<<<640, 256, 0, stream>>>(Whh_f, Whh_b, bih_f, bhh_f, bih_b, bhh_b,
                                      qWf, qWb, scf, scb, biasf, biasb,
                                      sents, mask, emb, embeds, out, bar);
    fused_main<<<256, 512, 0, stream>>>(embeds, Wih_f, Wih_b, biasf, biasb, gxf, gxb,
                                        qWf, qWb, scf, scb, hall,
                                        Ws, uArr, vArr, W1, b1, W2, b2, p1, p2,
                                        bs, prior, heads, out, bar);
    (void)in_sizes; (void)n_in; (void)out_size; (void)ws_size;
}

// Round 15
// 257.415 us; speedup vs baseline: 1.6547x; 1.6547x over previous
//
#include <hip/hip_runtime.h>
#include <hip/hip_bf16.h>
#include <math.h>

#define L2E 1.44269504f
#define LN2 0.69314718f
#define TSTRIDE 68

typedef __attribute__((ext_vector_type(2))) float floatx2;

__device__ __forceinline__ float sigf(float x){ return 1.0f/(1.0f+expf(-x)); }

__device__ __forceinline__ float quad_max(float x) {
    x = fmaxf(x, __int_as_float(__builtin_amdgcn_mov_dpp(__float_as_int(x), 0xB1, 0xF, 0xF, true)));
    x = fmaxf(x, __int_as_float(__builtin_amdgcn_mov_dpp(__float_as_int(x), 0x4E, 0xF, 0xF, true)));
    return x;
}
// 8-lane reductions, pure DPP (xor1, xor2, half-row mirror)
__device__ __forceinline__ float oct_max(float x) {
    x = fmaxf(x, __int_as_float(__builtin_amdgcn_mov_dpp(__float_as_int(x), 0xB1, 0xF, 0xF, true)));
    x = fmaxf(x, __int_as_float(__builtin_amdgcn_mov_dpp(__float_as_int(x), 0x4E, 0xF, 0xF, true)));
    x = fmaxf(x, __int_as_float(__builtin_amdgcn_mov_dpp(__float_as_int(x), 0x141, 0xF, 0xF, true)));
    return x;
}
__device__ __forceinline__ float oct_sum(float x) {
    x += __int_as_float(__builtin_amdgcn_mov_dpp(__float_as_int(x), 0xB1, 0xF, 0xF, true));
    x += __int_as_float(__builtin_amdgcn_mov_dpp(__float_as_int(x), 0x4E, 0xF, 0xF, true));
    x += __int_as_float(__builtin_amdgcn_mov_dpp(__float_as_int(x), 0x141, 0xF, 0xF, true));
    return x;
}

// Grid barrier v2. Round-14's version polled with atomicAdd(cnt,0) -- an RMW
// that ping-pongs exclusive line ownership across 8 XCD L2s from 256 spinners
// and starves arrivals (~80 us/barrier, VALUBusy 11%). Fix: arrivals are the
// ONLY RMWs; polling is a relaxed agent-scope LOAD (no ownership). Fences by
// thread 0 only (legal: __syncthreads drains per-wave vmcnt; agent fence
// writes back this XCD's L2 which holds all block writes).
__device__ __forceinline__ void gbar(unsigned* cnt, unsigned target) {
    __syncthreads();
    if (threadIdx.x == 0) {
        __threadfence();
        atomicAdd(cnt, 1u);
        while (__hip_atomic_load(cnt, __ATOMIC_RELAXED, __HIP_MEMORY_SCOPE_AGENT) < target)
            __builtin_amdgcn_s_sleep(16);
        __threadfence();
    }
    __syncthreads();
}

// ---------------------------------------------------------------- prep: embed + bias + fp8 pack + barrier init
__global__ __launch_bounds__(256) void prep_all(const float* __restrict__ Whh_f, const float* __restrict__ Whh_b,
                             const float* __restrict__ bih_f, const float* __restrict__ bhh_f,
                             const float* __restrict__ bih_b, const float* __restrict__ bhh_b,
                             uint4* __restrict__ qWf, uint4* __restrict__ qWb,
                             float* __restrict__ scf, float* __restrict__ scb,
                             float* __restrict__ biasf, float* __restrict__ biasb,
                             const int* __restrict__ sents, const float* __restrict__ mask,
                             const float* __restrict__ emb, float* __restrict__ embeds,
                             float* __restrict__ out, unsigned* __restrict__ bar) {
    int tid = threadIdx.x;
    if (blockIdx.x < 512) {
        int bl = blockIdx.x;
        const int*   srow = sents + bl*32;
        const float* mrow = mask  + bl*32;
        float acc = 0.0f, el = 0.0f;
        for (int w = 0; w < 32; ++w) {
            float m = mrow[w];
            el  += m;
            acc += emb[(size_t)srow[w]*256 + tid] * m;
        }
        float den = el + (el == 0.0f ? 1.0f : 0.0f);
        embeds[bl*256 + tid] = acc / den;
        if (bl == 0)      { for (int q = tid; q < 1024; q += 256) biasf[q] = bih_f[q] + bhh_f[q]; }
        else if (bl == 1) { for (int q = tid; q < 1024; q += 256) biasb[q] = bih_b[q] + bhh_b[q]; }
        else if (bl == 2 && tid == 0) { out[0] = 0.0f; atomicExch(bar, 0u); }
    } else {
        int pb  = blockIdx.x - 512;      // 0..127
        int dir = pb >> 6;
        int cg  = pb & 63;               // cell group of 4
        const float* W = dir ? Whh_b : Whh_f;
        uint4* qW = dir ? qWb : qWf;
        float* sc = dir ? scb : scf;
        __shared__ float Wl[16][260];    // 16 rows (4 gates x 4 cells), padded
        __shared__ float sL[16];         // row scales [g*4+jj]
        #pragma unroll
        for (int lr = 0; lr < 16; ++lr) {
            int g = lr >> 2, jj = lr & 3;
            int rowid = g*256 + cg*4 + jj;
            Wl[lr][tid] = W[(size_t)rowid*256 + tid];
        }
        __syncthreads();
        if (tid < 64) {
            int lr = tid >> 2, sub = tid & 3;
            float mx = 0.0f;
            for (int m = 0; m < 64; ++m) mx = fmaxf(mx, fabsf(Wl[lr][sub*64 + m]));
            mx = quad_max(mx);
            if (sub == 0) sL[lr] = mx * (1.0f/240.0f) + 1e-30f;
        }
        __syncthreads();
        int k4 = tid >> 2, jj = tid & 3;
        float is0 = 1.0f / sL[0*4 + jj];
        float is1 = 1.0f / sL[1*4 + jj];
        float is2 = 1.0f / sL[2*4 + jj];
        float is3 = 1.0f / sL[3*4 + jj];
        uint4 q;
        unsigned int* qq = (unsigned int*)&q;
        #pragma unroll
        for (int kk = 0; kk < 4; ++kk) {
            int k = k4*4 + kk;
            int d = 0;
            d = __builtin_amdgcn_cvt_pk_fp8_f32(Wl[0*4+jj][k]*is0, Wl[1*4+jj][k]*is1, d, false);
            d = __builtin_amdgcn_cvt_pk_fp8_f32(Wl[2*4+jj][k]*is2, Wl[3*4+jj][k]*is3, d, true);
            qq[kk] = (unsigned int)d;
        }
        qW[k4*256 + cg*4 + jj] = q;
        if (tid < 16) {
            int g = tid >> 2, j2 = tid & 3;
            sc[(cg*4 + j2)*4 + g] = sL[g*4 + j2];
        }
    }
}

// ---------------------------------------------------------------- fused: gemm_ih -> lstm -> post -> eisner
// 256 blocks x 512 threads; 3 grid barriers replace 3 kernel launches.
// Co-residency safe by capacity: 2 x 53.75KB LDS <= 160KB -> all 256 blocks
// resident under any placement.
__global__ __launch_bounds__(512, 2) void fused_main(
        const float* __restrict__ embeds,
        const float* __restrict__ Wih_f, const float* __restrict__ Wih_b,
        const float* __restrict__ biasf, const float* __restrict__ biasb,
        float* __restrict__ gxf, float* __restrict__ gxb,
        const uint4* __restrict__ qWf, const uint4* __restrict__ qWb,
        const float* __restrict__ scf, const float* __restrict__ scb,
        float* __restrict__ hall,
        const float* __restrict__ Ws, float* __restrict__ u, float* __restrict__ v,
        const float* __restrict__ W1, const float* __restrict__ b1,
        const float* __restrict__ W2, const float* __restrict__ b2,
        float* __restrict__ p1, float* __restrict__ p2,
        const float* __restrict__ bs, const float* __restrict__ prior,
        const int* __restrict__ heads,
        float* __restrict__ out, unsigned* __restrict__ bar) {
    __shared__ __align__(16) float SMEM[3*64*TSTRIDE + 64];
    __shared__ float su[64], sv[64], lseSb[64], sBest[1];
    __shared__ float ru2[2][4], rv2[2][4];
    int tid = threadIdx.x;
    int blk = blockIdx.x;

    // ================= F1: gemm_ih -- one 64x64 tile per block, 512 thr
    {
        int dir  = blk >> 7;
        int rest = blk & 127;
        int bx = rest >> 4, by = rest & 15;
        const float* A    = embeds;
        const float* Bm   = dir ? Wih_b : Wih_f;
        const float* bias = dir ? biasb : biasf;
        float* C          = dir ? gxb : gxf;
        const int N = 1024, K = 256;
        float* As = SMEM;              // [32][68]
        float* Bs = SMEM + 32*68;      // [32][68]
        int tx = tid & 15, ty = tid >> 4;        // ty 0..31 -> 2 rows each
        int row0 = bx * 64, col0 = by * 64;
        float acc[2][4];
        #pragma unroll
        for (int r = 0; r < 2; ++r)
            #pragma unroll
            for (int c = 0; c < 4; ++c) acc[r][c] = 0.0f;
        int lr = tid >> 3;             // 0..63
        int lc = (tid & 7) * 4;        // 0,4,..,28
        for (int k0 = 0; k0 < K; k0 += 32) {
            float4 a0 = *(const float4*)(A  + (size_t)(row0+lr)*K + k0 + lc);
            float4 b0 = *(const float4*)(Bm + (size_t)(col0+lr)*K + k0 + lc);
            As[(lc  )*68 + lr] = a0.x; As[(lc+1)*68 + lr] = a0.y;
            As[(lc+2)*68 + lr] = a0.z; As[(lc+3)*68 + lr] = a0.w;
            Bs[(lc  )*68 + lr] = b0.x; Bs[(lc+1)*68 + lr] = b0.y;
            Bs[(lc+2)*68 + lr] = b0.z; Bs[(lc+3)*68 + lr] = b0.w;
            __syncthreads();
            #pragma unroll
            for (int kc = 0; kc < 32; ++kc) {
                float2 xa = *(const float2*)&As[kc*68 + ty*2];
                float4 xb = *(const float4*)&Bs[kc*68 + tx*4];
                acc[0][0] = fmaf(xa.x, xb.x, acc[0][0]);
                acc[0][1] = fmaf(xa.x, xb.y, acc[0][1]);
                acc[0][2] = fmaf(xa.x, xb.z, acc[0][2]);
                acc[0][3] = fmaf(xa.x, xb.w, acc[0][3]);
                acc[1][0] = fmaf(xa.y, xb.x, acc[1][0]);
                acc[1][1] = fmaf(xa.y, xb.y, acc[1][1]);
                acc[1][2] = fmaf(xa.y, xb.z, acc[1][2]);
                acc[1][3] = fmaf(xa.y, xb.w, acc[1][3]);
            }
            __syncthreads();
        }
        float4 bv = *(const float4*)&bias[col0 + tx*4];
        #pragma unroll
        for (int r = 0; r < 2; ++r) {
            float4 o;
            o.x = acc[r][0] + bv.x; o.y = acc[r][1] + bv.y;
            o.z = acc[r][2] + bv.z; o.w = acc[r][3] + bv.w;
            *(float4*)(C + (size_t)(row0 + ty*2 + r)*N + col0 + tx*4) = o;
        }
    }
    gbar(bar, 256);

    // ================= F2: LSTM recurrence (2-way K split, 2 reps)
    {
        int lb   = blk;
        int rep  = lb >> 7;
        lb &= 127;
        int dir  = lb >> 6;
        int pos  = lb & 63;
        int j    = tid & 255;
        int half = tid >> 8;
        const float* gx = dir ? gxb : gxf;
        const uint4* qW = dir ? qWb : qWf;
        float4 sc = ((const float4*)(dir ? scb : scf))[j];
        float* hs = SMEM;                              // 256 floats
        float (*part)[4] = (float(*)[4])(SMEM + 256);  // 256x4 floats
        if (tid < 256) hs[tid] = 0.0f;
        float cellc = 0.0f;
        __syncthreads();
        const uint4* qWh = qW + (half << 13);
        const float* hsh = hs + (half << 7);
        for (int s = 0; s < 8; ++s) {
            int t = dir ? (7 - s) : s;
            const float* g0 = gx + (size_t)(t*64 + pos)*1024;
            float ai = 0.0f, af = 0.0f, ag = 0.0f, ao = 0.0f;
            if (half == 0) { ai = g0[j]; af = g0[256+j]; ag = g0[512+j]; ao = g0[768+j]; }
            float qi = 0.0f, qf = 0.0f, qg = 0.0f, qo = 0.0f;
            #pragma unroll 8
            for (int k4 = 0; k4 < 32; ++k4) {
                uint4 wq = qWh[(k4 << 8) + j];
                float4 hp = *(const float4*)&hsh[k4*4];
                floatx2 pa, pb;
                pa = __builtin_amdgcn_cvt_pk_f32_fp8(wq.x, false);
                pb = __builtin_amdgcn_cvt_pk_f32_fp8(wq.x, true);
                qi = fmaf(pa.x, hp.x, qi); qf = fmaf(pa.y, hp.x, qf);
                qg = fmaf(pb.x, hp.x, qg); qo = fmaf(pb.y, hp.x, qo);
                pa = __builtin_amdgcn_cvt_pk_f32_fp8(wq.y, false);
                pb = __builtin_amdgcn_cvt_pk_f32_fp8(wq.y, true);
                qi = fmaf(pa.x, hp.y, qi); qf = fmaf(pa.y, hp.y, qf);
                qg = fmaf(pb.x, hp.y, qg); qo = fmaf(pb.y, hp.y, qo);
                pa = __builtin_amdgcn_cvt_pk_f32_fp8(wq.z, false);
                pb = __builtin_amdgcn_cvt_pk_f32_fp8(wq.z, true);
                qi = fmaf(pa.x, hp.z, qi); qf = fmaf(pa.y, hp.z, qf);
                qg = fmaf(pb.x, hp.z, qg); qo = fmaf(pb.y, hp.z, qo);
                pa = __builtin_amdgcn_cvt_pk_f32_fp8(wq.w, false);
                pb = __builtin_amdgcn_cvt_pk_f32_fp8(wq.w, true);
                qi = fmaf(pa.x, hp.w, qi); qf = fmaf(pa.y, hp.w, qf);
                qg = fmaf(pb.x, hp.w, qg); qo = fmaf(pb.y, hp.w, qo);
            }
            if (half) { part[j][0] = qi; part[j][1] = qf; part[j][2] = qg; part[j][3] = qo; }
            __syncthreads();
            if (half == 0) {
                float4 pr = *(const float4*)&part[j][0];
                ai = fmaf(sc.x, qi + pr.x, ai);
                af = fmaf(sc.y, qf + pr.y, af);
                ag = fmaf(sc.z, qg + pr.z, ag);
                ao = fmaf(sc.w, qo + pr.w, ao);
                cellc = sigf(af)*cellc + sigf(ai)*tanhf(ag);
                float h0 = sigf(ao)*tanhf(cellc);
                hs[j] = h0;
                if (rep == 0) hall[(size_t)(t*64 + pos)*512 + dir*256 + j] = h0;
            }
            __syncthreads();
        }
    }
    gbar(bar, 512);

    // ================= F3: uv (blocks 128-255, 4 units each) / p1,p2 gemm32 (blocks 0-127)
    if (blk >= 128) {
        int h  = tid >> 8;        // half handles its own uv unit
        int t2 = tid & 255;
        for (int p = 0; p < 2; ++p) {
            int bi = (blk - 128)*4 + p*2 + h;      // 0..511
            int i  = bi & 63;
            float pu = 0.0f, pv = 0.0f;
            for (int q = t2; q < 1536; q += 256) {
                int seg = q >> 9, kk = q & 511;
                float tv = 0.0f;
                if (seg == 0)       tv = hall[(size_t)bi*512 + kk];
                else if (seg == 1)  { if (i > 0)  tv = hall[(size_t)(bi-1)*512 + kk]; }
                else                { if (i < 63) tv = hall[(size_t)(bi+1)*512 + kk]; }
                pu = fmaf(tv, Ws[q],        pu);
                pv = fmaf(tv, Ws[1536 + q], pv);
            }
            for (int off = 32; off; off >>= 1) { pu += __shfl_xor(pu, off); pv += __shfl_xor(pv, off); }
            int wv = t2 >> 6, lane = t2 & 63;
            if (lane == 0) { ru2[h][wv] = pu; rv2[h][wv] = pv; }
            __syncthreads();
            if (t2 == 0) {
                u[bi] = ru2[h][0]+ru2[h][1]+ru2[h][2]+ru2[h][3];
                v[bi] = rv2[h][0]+rv2[h][1]+rv2[h][2]+rv2[h][3];
            }
            __syncthreads();
        }
    } else {
        int sel = blk >> 6, un = blk & 63;         // 64 tiles per matrix
        const float* A    = hall;
        const float* Bm   = sel ? W2 : W1;
        const float* bias = sel ? b2 : b1;
        float* C          = sel ? p2 : p1;
        int bx = un >> 2, by = un & 3;
        const int N = 128, K = 512;
        float* As2 = SMEM;             // [32][36]
        float* Bs2 = SMEM + 32*36;
        int tx = tid & 15, ty = (tid >> 4) & 15;
        int row0 = bx * 32, col0 = by * 32;
        float a00 = 0.f, a01 = 0.f, a10 = 0.f, a11 = 0.f;
        int lr = (tid >> 3) & 31;
        int lc = (tid & 7) * 4;
        for (int k0 = 0; k0 < K; k0 += 32) {
            if (tid < 256) {
                float4 av = *(const float4*)(A  + (size_t)(row0+lr)*K + k0 + lc);
                float4 bv = *(const float4*)(Bm + (size_t)(col0+lr)*K + k0 + lc);
                As2[(lc  )*36 + lr] = av.x; As2[(lc+1)*36 + lr] = av.y;
                As2[(lc+2)*36 + lr] = av.z; As2[(lc+3)*36 + lr] = av.w;
                Bs2[(lc  )*36 + lr] = bv.x; Bs2[(lc+1)*36 + lr] = bv.y;
                Bs2[(lc+2)*36 + lr] = bv.z; Bs2[(lc+3)*36 + lr] = bv.w;
            }
            __syncthreads();
            if (tid < 256) {
                #pragma unroll
                for (int kc = 0; kc < 32; ++kc) {
                    float2 xa = *(const float2*)&As2[kc*36 + ty*2];
                    float2 xb = *(const float2*)&Bs2[kc*36 + tx*2];
                    a00 = fmaf(xa.x, xb.x, a00);
                    a01 = fmaf(xa.x, xb.y, a01);
                    a10 = fmaf(xa.y, xb.x, a10);
                    a11 = fmaf(xa.y, xb.y, a11);
                }
            }
            __syncthreads();
        }
        if (tid < 256) {
            float2 bv = *(const float2*)&bias[col0 + tx*2];
            float2 o0; o0.x = a00 + bv.x; o0.y = a01 + bv.y;
            float2 o1; o1.x = a10 + bv.x; o1.y = a11 + bv.y;
            *(float2*)(C + (size_t)(row0 + ty*2    )*N + col0 + tx*2) = o0;
            *(float2*)(C + (size_t)(row0 + ty*2 + 1)*N + col0 + tx*2) = o1;
        }
    }
    gbar(bar, 768);

    // ================= F4: Eisner (round-13 linear-domain body)
    {
        int b   = blk & 7;
        int rep = blk >> 3;
        float* T1 = &SMEM[0];
        float* T2 = &SMEM[64*TSTRIDE];
        float* T3 = &SMEM[2*64*TSTRIDE];
        float bsv = bs[0];
        if (tid < 64) {
            su[tid] = u[b*64 + tid];
            sv[tid] = v[b*64 + tid];
        }
        const float4* g1 = (const float4*)(p1 + (size_t)b*8192);
        const float4* g2 = (const float4*)(p2 + (size_t)b*8192);
        float4* s1p = (float4*)SMEM;
        float4* s2p = (float4*)(SMEM + 64*TSTRIDE);
        int r   = tid >> 3;
        int sub = tid & 7;
        float acc[8];
        #pragma unroll
        for (int q = 0; q < 8; ++q) acc[q] = 0.0f;
        __syncthreads();     // all F3 LDS use done before restage
        for (int p = 0; p < 2; ++p) {
            #pragma unroll
            for (int f0 = 0; f0 < 4; ++f0) {
                int f = f0*512 + tid;
                int half = f >> 10;
                int ff = f & 1023;
                int row = ff >> 4, c4 = ff & 15;
                float4 vv = (half ? g2 : g1)[row*32 + (p<<4) + c4];
                (half ? s2p : s1p)[row*17 + c4] = vv;
            }
            __syncthreads();
            #pragma unroll 2
            for (int k4 = 0; k4 < 16; ++k4) {
                float4 a = s1p[r*17 + k4];
                #pragma unroll
                for (int q = 0; q < 8; ++q) {
                    float4 bv = s2p[(sub + (q<<3))*17 + k4];
                    acc[q] = fmaf(a.x, bv.x, acc[q]);
                    acc[q] = fmaf(a.y, bv.y, acc[q]);
                    acc[q] = fmaf(a.z, bv.z, acc[q]);
                    acc[q] = fmaf(a.w, bv.w, acc[q]);
                }
            }
            __syncthreads();
        }
        float pm = acc[0];
        #pragma unroll
        for (int q = 1; q < 8; ++q) pm = fmaxf(pm, acc[q]);
        pm = oct_max(pm);
        float ps = 0.0f;
        #pragma unroll
        for (int q = 0; q < 8; ++q) ps += exp2f((acc[q] - pm) * L2E);
        ps = oct_sum(ps);
        if (sub == 0) lseSb[r] = pm + log2f(ps) * LN2;
        float* Sl = SMEM;
        #pragma unroll
        for (int q = 0; q < 8; ++q) Sl[r*66 + sub + (q<<3)] = acc[q];
        __syncthreads();
        if (tid < 64) {
            int m = tid;
            float gv = -INFINITY;
            if (m >= 1) {
                int hd = heads[b*64 + m];
                gv = su[hd] + sv[m] + bsv + (Sl[hd*66 + m] - lseSb[hd])
                   + prior[(size_t)(b*64 + hd)*64 + m] * (1.0f/64.0f);
            }
            float mm = gv;
            for (int off = 32; off; off >>= 1) mm = fmaxf(mm, __shfl_xor(mm, off));
            float se = (m >= 1) ? exp2f((gv - mm) * L2E) : 0.0f;
            for (int off = 32; off; off >>= 1) se += __shfl_xor(se, off);
            if (m == 0) sBest[0] = mm + log2f(se) * LN2;
        }
        __syncthreads();
        for (int q = tid; q < 3*64*TSTRIDE; q += 512) SMEM[q] = 0.0f;
        __syncthreads();
        if (tid < 64) {
            T1[tid*TSTRIDE + tid] = 1.0f;
            if (tid >= 1) T2[tid*TSTRIDE + tid-1] = 1.0f;
        }
        __syncthreads();
        int i = r;
        int k0 = i & ~3;
        float sui_b = su[i] + bsv;
        float svi_b = sv[i] + bsv;
        const float* t1i = &T1[i*TSTRIDE];
        const float* t2i = &T2[i*TSTRIDE];
        const float* t3i = &T3[i*TSTRIDE];
        for (int w = 1; w < 64; ++w) {
            int ns = 64 - w;
            if (i < ns) {
                int j = i + w;
                const float* t1j = &T1[j*TSTRIDE];
                const float* t2j = &T2[j*TSTRIDE];
                const float* t3j = &T3[j*TSTRIDE];
                float eDr = exp2f((sui_b + sv[j]) * L2E);
                float eDl = exp2f((su[j] + svi_b) * L2E);
                float s1 = 0.0f, sr = 0.0f, sl = 0.0f;
                #pragma unroll
                for (int t = 0; t < 2; ++t) {
                    int k = k0 + ((t << 3) + sub) * 4;
                    if (k < j) {
                        float4 a1  = *(const float4*)&t1i[k];
                        float4 b1  = *(const float4*)&t2j[k];
                        float4 a2  = *(const float4*)&t3i[k];
                        float4 b2v = *(const float4*)&t1j[k];
                        float4 a3  = *(const float4*)&t2i[k];
                        float4 b3  = *(const float4*)&t3j[k];
                        #pragma unroll
                        for (int c = 0; c < 4; ++c) {
                            s1 = fmaf(((const float*)&a1)[c], ((const float*)&b1)[c],  s1);
                            sr = fmaf(((const float*)&a2)[c], ((const float*)&b2v)[c], sr);
                            sl = fmaf(((const float*)&a3)[c], ((const float*)&b3)[c],  sl);
                        }
                    }
                }
                s1 = oct_sum(s1);
                sr = oct_sum(sr);
                sl = oct_sum(sl);
                if (sub == 0) {
                    float Ir = 0.25f * s1 * eDr;
                    float Il = 0.25f * s1 * eDl;
                    float Cr = sr + Ir;
                    float Cl = sl + Il;
                    T3[i*TSTRIDE + j] = Ir;
                    T1[i*TSTRIDE + j] = Cr;
                    T1[j*TSTRIDE + i] = Cr;
                    T3[j*TSTRIDE + i] = Il;
                    T2[i*TSTRIDE + j] = Cl;
                    if (i >= 1) T2[j*TSTRIDE + i-1] = Cl;
                }
            }
            __syncthreads();
        }
        if (rep == 0 && tid == 0) {
            float logZv = (log2f(T1[0*TSTRIDE + 63]) + 126.0f) * LN2;
            atomicAdd(out, -(sBest[0] - logZv) * 0.125f);
        }
    }
}

// ---------------------------------------------------------------- launch
extern "C" void kernel_launch(void* const* d_in, const int* in_sizes, int n_in,
                              void* d_out, int out_size, void* d_ws, size_t ws_size,
                              hipStream_t stream) {
    const int*   sents = (const int*)  d_in[0];
    const float* mask  = (const float*)d_in[1];
    const float* prior = (const float*)d_in[2];
    const int*   heads = (const int*)  d_in[3];
    const float* emb   = (const float*)d_in[4];
    const float* Wih_f = (const float*)d_in[5];
    const float* Whh_f = (const float*)d_in[6];
    const float* bih_f = (const float*)d_in[7];
    const float* bhh_f = (const float*)d_in[8];
    const float* Wih_b = (const float*)d_in[9];
    const float* Whh_b = (const float*)d_in[10];
    const float* bih_b = (const float*)d_in[11];
    const float* bhh_b = (const float*)d_in[12];
    const float* W1    = (const float*)d_in[13];
    const float* b1    = (const float*)d_in[14];
    const float* W2    = (const float*)d_in[15];
    const float* b2    = (const float*)d_in[16];
    const float* Ws    = (const float*)d_in[17];
    const float* bs    = (const float*)d_in[18];
    float* out = (float*)d_out;

    char* w = (char*)d_ws;
    float* embeds = (float*)(w + 0);                 // 512 KB
    float* gxf    = (float*)(w + 524288);            // 2 MB
    float* gxb    = (float*)(w + 2621440);           // 2 MB
    uint4* qWf    = (uint4*)(w + 4718592);           // 256 KB
    uint4* qWb    = (uint4*)(w + 4980736);           // 256 KB
    float* scf    = (float*)(w + 5242880);           // 4 KB
    float* scb    = (float*)(w + 5246976);           // 4 KB
    float* biasf  = (float*)(w + 5767168);           // 4 KB
    float* biasb  = (float*)(w + 5771264);           // 4 KB
    float* hall   = (float*)(w + 5775360);           // 1 MB
    float* uArr   = (float*)(w + 6823936);
    float* vArr   = (float*)(w + 6825984);
    float* p1     = (float*)(w + 6828032);
    float* p2     = (float*)(w + 7090176);
    unsigned* bar = (unsigned*)(w + 7352320);        // grid-barrier counter

    prep_all<<<640, 256, 0, stream>>>(Whh_f, Whh_b, bih_f, bhh_f, bih_b, bhh_b,
                                      qWf, qWb, scf, scb, biasf, biasb,
                                      sents, mask, emb, embeds, out, bar);
    fused_main<<<256, 512, 0, stream>>>(embeds, Wih_f, Wih_b, biasf, biasb, gxf, gxb,
                                        qWf, qWb, scf, scb, hall,
                                        Ws, uArr, vArr, W1, b1, W2, b2, p1, p2,
                                        bs, prior, heads, out, bar);
    (void)in_sizes; (void)n_in; (void)out_size; (void)ws_size;
}

// Round 16
// 213.605 us; speedup vs baseline: 1.9941x; 1.2051x over previous
//
#include <hip/hip_runtime.h>
#include <hip/hip_bf16.h>
#include <math.h>

#define L2E 1.44269504f
#define LN2 0.69314718f
#define TSTRIDE 68

typedef __attribute__((ext_vector_type(2))) float floatx2;

__device__ __forceinline__ float sigf(float x){ return 1.0f/(1.0f+expf(-x)); }

__device__ __forceinline__ float quad_max(float x) {
    x = fmaxf(x, __int_as_float(__builtin_amdgcn_mov_dpp(__float_as_int(x), 0xB1, 0xF, 0xF, true)));
    x = fmaxf(x, __int_as_float(__builtin_amdgcn_mov_dpp(__float_as_int(x), 0x4E, 0xF, 0xF, true)));
    return x;
}
// 8-lane (aligned consecutive group) reductions -- PURE DPP, no LDS:
// xor1 = quad_perm swap-adjacent (0xB1), xor2 = quad_perm swap-pairs (0x4E),
// quad<->quad exchange within the 8-lane half-row = row_half_mirror (0x141).
__device__ __forceinline__ float oct_max(float x) {
    x = fmaxf(x, __int_as_float(__builtin_amdgcn_mov_dpp(__float_as_int(x), 0xB1, 0xF, 0xF, true)));
    x = fmaxf(x, __int_as_float(__builtin_amdgcn_mov_dpp(__float_as_int(x), 0x4E, 0xF, 0xF, true)));
    x = fmaxf(x, __int_as_float(__builtin_amdgcn_mov_dpp(__float_as_int(x), 0x141, 0xF, 0xF, true)));
    return x;
}
__device__ __forceinline__ float oct_sum(float x) {
    x += __int_as_float(__builtin_amdgcn_mov_dpp(__float_as_int(x), 0xB1, 0xF, 0xF, true));
    x += __int_as_float(__builtin_amdgcn_mov_dpp(__float_as_int(x), 0x4E, 0xF, 0xF, true));
    x += __int_as_float(__builtin_amdgcn_mov_dpp(__float_as_int(x), 0x141, 0xF, 0xF, true));
    return x;
}

// ---------------------------------------------------------------- prep: embed + bias + coalesced fp8 pack
__global__ __launch_bounds__(256) void prep_all(const float* __restrict__ Whh_f, const float* __restrict__ Whh_b,
                             const float* __restrict__ bih_f, const float* __restrict__ bhh_f,
                             const float* __restrict__ bih_b, const float* __restrict__ bhh_b,
                             uint4* __restrict__ qWf, uint4* __restrict__ qWb,
                             float* __restrict__ scf, float* __restrict__ scb,
                             float* __restrict__ biasf, float* __restrict__ biasb,
                             const int* __restrict__ sents, const float* __restrict__ mask,
                             const float* __restrict__ emb, float* __restrict__ embeds,
                             float* __restrict__ out) {
    int tid = threadIdx.x;
    if (blockIdx.x < 512) {
        int bl = blockIdx.x;
        const int*   srow = sents + bl*32;
        const float* mrow = mask  + bl*32;
        float acc = 0.0f, el = 0.0f;
        for (int w = 0; w < 32; ++w) {
            float m = mrow[w];
            el  += m;
            acc += emb[(size_t)srow[w]*256 + tid] * m;
        }
        float den = el + (el == 0.0f ? 1.0f : 0.0f);
        embeds[bl*256 + tid] = acc / den;
        if (bl == 0)      { for (int q = tid; q < 1024; q += 256) biasf[q] = bih_f[q] + bhh_f[q]; }
        else if (bl == 1) { for (int q = tid; q < 1024; q += 256) biasb[q] = bih_b[q] + bhh_b[q]; }
        else if (bl == 2 && tid == 0) out[0] = 0.0f;
    } else {
        int pb  = blockIdx.x - 512;      // 0..127
        int dir = pb >> 6;
        int cg  = pb & 63;               // cell group of 4
        const float* W = dir ? Whh_b : Whh_f;
        uint4* qW = dir ? qWb : qWf;
        float* sc = dir ? scb : scf;
        __shared__ float Wl[16][260];    // 16 rows (4 gates x 4 cells), padded
        __shared__ float sL[16];         // row scales [g*4+jj]
        #pragma unroll
        for (int lr = 0; lr < 16; ++lr) {
            int g = lr >> 2, jj = lr & 3;
            int rowid = g*256 + cg*4 + jj;
            Wl[lr][tid] = W[(size_t)rowid*256 + tid];
        }
        __syncthreads();
        if (tid < 64) {
            int lr = tid >> 2, sub = tid & 3;
            float mx = 0.0f;
            for (int m = 0; m < 64; ++m) mx = fmaxf(mx, fabsf(Wl[lr][sub*64 + m]));
            mx = quad_max(mx);
            if (sub == 0) sL[lr] = mx * (1.0f/240.0f) + 1e-30f;
        }
        __syncthreads();
        int k4 = tid >> 2, jj = tid & 3;
        float is0 = 1.0f / sL[0*4 + jj];
        float is1 = 1.0f / sL[1*4 + jj];
        float is2 = 1.0f / sL[2*4 + jj];
        float is3 = 1.0f / sL[3*4 + jj];
        uint4 q;
        unsigned int* qq = (unsigned int*)&q;
        #pragma unroll
        for (int kk = 0; kk < 4; ++kk) {
            int k = k4*4 + kk;
            int d = 0;
            d = __builtin_amdgcn_cvt_pk_fp8_f32(Wl[0*4+jj][k]*is0, Wl[1*4+jj][k]*is1, d, false);
            d = __builtin_amdgcn_cvt_pk_fp8_f32(Wl[2*4+jj][k]*is2, Wl[3*4+jj][k]*is3, d, true);
            qq[kk] = (unsigned int)d;
        }
        qW[k4*256 + cg*4 + jj] = q;
        if (tid < 16) {
            int g = tid >> 2, j2 = tid & 3;
            sc[(cg*4 + j2)*4 + g] = sL[g*4 + j2];
        }
    }
}

// ---------------------------------------------------------------- 64x64 GEMM body, 4x4 micro-tile
// Keep for gemm_ih: round-11 measured the 32-tile variant REGRESSING ~7 us
// there ("more blocks" only pays when blocks < CUs; gemm_ih has 256).
__device__ __forceinline__ void gemm64_body(const float* __restrict__ A,
                                            const float* __restrict__ Bm,
                                            const float* __restrict__ bias,
                                            float* __restrict__ C,
                                            int N, int K, int bx, int by) {
    __shared__ __align__(16) float As[32][68];
    __shared__ __align__(16) float Bs[32][68];
    int tid = threadIdx.x;
    int tx = tid & 15, ty = tid >> 4;
    int row0 = bx * 64, col0 = by * 64;
    float acc[4][4];
    #pragma unroll
    for (int r = 0; r < 4; ++r)
        #pragma unroll
        for (int c = 0; c < 4; ++c) acc[r][c] = 0.0f;
    int lr = tid >> 2;
    int lc = (tid & 3) * 8;
    for (int k0 = 0; k0 < K; k0 += 32) {
        float4 a0 = *(const float4*)(A  + (size_t)(row0+lr)*K + k0 + lc);
        float4 a1 = *(const float4*)(A  + (size_t)(row0+lr)*K + k0 + lc + 4);
        float4 b0 = *(const float4*)(Bm + (size_t)(col0+lr)*K + k0 + lc);
        float4 b1 = *(const float4*)(Bm + (size_t)(col0+lr)*K + k0 + lc + 4);
        As[lc  ][lr] = a0.x; As[lc+1][lr] = a0.y; As[lc+2][lr] = a0.z; As[lc+3][lr] = a0.w;
        As[lc+4][lr] = a1.x; As[lc+5][lr] = a1.y; As[lc+6][lr] = a1.z; As[lc+7][lr] = a1.w;
        Bs[lc  ][lr] = b0.x; Bs[lc+1][lr] = b0.y; Bs[lc+2][lr] = b0.z; Bs[lc+3][lr] = b0.w;
        Bs[lc+4][lr] = b1.x; Bs[lc+5][lr] = b1.y; Bs[lc+6][lr] = b1.z; Bs[lc+7][lr] = b1.w;
        __syncthreads();
        #pragma unroll
        for (int kc = 0; kc < 32; ++kc) {
            float4 xa = *(const float4*)&As[kc][ty*4];
            float4 xb = *(const float4*)&Bs[kc][tx*4];
            acc[0][0] = fmaf(xa.x, xb.x, acc[0][0]);
            acc[0][1] = fmaf(xa.x, xb.y, acc[0][1]);
            acc[0][2] = fmaf(xa.x, xb.z, acc[0][2]);
            acc[0][3] = fmaf(xa.x, xb.w, acc[0][3]);
            acc[1][0] = fmaf(xa.y, xb.x, acc[1][0]);
            acc[1][1] = fmaf(xa.y, xb.y, acc[1][1]);
            acc[1][2] = fmaf(xa.y, xb.z, acc[1][2]);
            acc[1][3] = fmaf(xa.y, xb.w, acc[1][3]);
            acc[2][0] = fmaf(xa.z, xb.x, acc[2][0]);
            acc[2][1] = fmaf(xa.z, xb.y, acc[2][1]);
            acc[2][2] = fmaf(xa.z, xb.z, acc[2][2]);
            acc[2][3] = fmaf(xa.z, xb.w, acc[2][3]);
            acc[3][0] = fmaf(xa.w, xb.x, acc[3][0]);
            acc[3][1] = fmaf(xa.w, xb.y, acc[3][1]);
            acc[3][2] = fmaf(xa.w, xb.z, acc[3][2]);
            acc[3][3] = fmaf(xa.w, xb.w, acc[3][3]);
        }
        __syncthreads();
    }
    float4 bv = bias ? *(const float4*)&bias[col0 + tx*4] : make_float4(0.f,0.f,0.f,0.f);
    #pragma unroll
    for (int r = 0; r < 4; ++r) {
        float4 o;
        o.x = acc[r][0] + bv.x; o.y = acc[r][1] + bv.y;
        o.z = acc[r][2] + bv.z; o.w = acc[r][3] + bv.w;
        *(float4*)(C + (size_t)(row0 + ty*4 + r)*N + col0 + tx*4) = o;
    }
}

// ---------------------------------------------------------------- 32x32 GEMM body, 2x2 micro-tile (p1/p2 only)
__device__ __forceinline__ void gemm32_body(const float* __restrict__ A,
                                            const float* __restrict__ Bm,
                                            const float* __restrict__ bias,
                                            float* __restrict__ C,
                                            int N, int K, int bx, int by) {
    __shared__ __align__(16) float As[32][36];
    __shared__ __align__(16) float Bs[32][36];
    int tid = threadIdx.x;
    int tx = tid & 15, ty = tid >> 4;
    int row0 = bx * 32, col0 = by * 32;
    float acc00 = 0.f, acc01 = 0.f, acc10 = 0.f, acc11 = 0.f;
    int lr = tid >> 3;            // 0..31
    int lc = (tid & 7) * 4;       // 0..28
    for (int k0 = 0; k0 < K; k0 += 32) {
        float4 a0 = *(const float4*)(A  + (size_t)(row0+lr)*K + k0 + lc);
        float4 b0 = *(const float4*)(Bm + (size_t)(col0+lr)*K + k0 + lc);
        As[lc  ][lr] = a0.x; As[lc+1][lr] = a0.y; As[lc+2][lr] = a0.z; As[lc+3][lr] = a0.w;
        Bs[lc  ][lr] = b0.x; Bs[lc+1][lr] = b0.y; Bs[lc+2][lr] = b0.z; Bs[lc+3][lr] = b0.w;
        __syncthreads();
        #pragma unroll
        for (int kc = 0; kc < 32; ++kc) {
            float2 xa = *(const float2*)&As[kc][ty*2];
            float2 xb = *(const float2*)&Bs[kc][tx*2];
            acc00 = fmaf(xa.x, xb.x, acc00);
            acc01 = fmaf(xa.x, xb.y, acc01);
            acc10 = fmaf(xa.y, xb.x, acc10);
            acc11 = fmaf(xa.y, xb.y, acc11);
        }
        __syncthreads();
    }
    float2 bv = *(const float2*)&bias[col0 + tx*2];
    float2 o0; o0.x = acc00 + bv.x; o0.y = acc01 + bv.y;
    float2 o1; o1.x = acc10 + bv.x; o1.y = acc11 + bv.y;
    *(float2*)(C + (size_t)(row0 + ty*2    )*N + col0 + tx*2) = o0;
    *(float2*)(C + (size_t)(row0 + ty*2 + 1)*N + col0 + tx*2) = o1;
}

__global__ __launch_bounds__(256) void gemm_ih(const float* __restrict__ embeds,
                                               const float* __restrict__ Wf, const float* __restrict__ Wb,
                                               const float* __restrict__ biasf, const float* __restrict__ biasb,
                                               float* __restrict__ gxf, float* __restrict__ gxb) {
    int dir = blockIdx.z;
    gemm64_body(embeds, dir ? Wb : Wf, dir ? biasb : biasf, dir ? gxb : gxf,
                1024, 256, blockIdx.x, blockIdx.y);
}

// ---------------------------------------------------------------- LSTM recurrence (fp8 weights, 2-way K split)
__global__ __launch_bounds__(512) void lstm_rec(const float* __restrict__ gxf,
                                                const float* __restrict__ gxb,
                                                const uint4* __restrict__ qWf,
                                                const uint4* __restrict__ qWb,
                                                const float* __restrict__ scf,
                                                const float* __restrict__ scb,
                                                float* __restrict__ hall) {
    int blk  = blockIdx.x;        // 0..255: (rep, dir, pos)
    int rep  = blk >> 7;
    blk &= 127;
    int dir  = blk >> 6;
    int pos  = blk & 63;
    int tid  = threadIdx.x;
    int j    = tid & 255;         // cell
    int half = tid >> 8;          // K half
    const float* gx = dir ? gxb : gxf;
    const uint4* qW = dir ? qWb : qWf;
    float4 sc = ((const float4*)(dir ? scb : scf))[j];
    __shared__ __align__(16) float hs[256];
    __shared__ __align__(16) float part[256][4];
    if (tid < 256) hs[tid] = 0.0f;
    float cellc = 0.0f;
    __syncthreads();
    const uint4* qWh = qW + (half << 13);       // + half*32*256
    const float* hsh = hs + (half << 7);        // + half*32*4
    for (int s = 0; s < 8; ++s) {
        int t = dir ? (7 - s) : s;
        const float* g0 = gx + (size_t)(t*64 + pos)*1024;
        float ai = 0.0f, af = 0.0f, ag = 0.0f, ao = 0.0f;
        if (half == 0) { ai = g0[j]; af = g0[256+j]; ag = g0[512+j]; ao = g0[768+j]; }
        float qi = 0.0f, qf = 0.0f, qg = 0.0f, qo = 0.0f;
        #pragma unroll 8
        for (int k4 = 0; k4 < 32; ++k4) {
            uint4 wq = qWh[(k4 << 8) + j];
            float4 hp = *(const float4*)&hsh[k4*4];
            floatx2 pa, pb;
            pa = __builtin_amdgcn_cvt_pk_f32_fp8(wq.x, false);
            pb = __builtin_amdgcn_cvt_pk_f32_fp8(wq.x, true);
            qi = fmaf(pa.x, hp.x, qi); qf = fmaf(pa.y, hp.x, qf);
            qg = fmaf(pb.x, hp.x, qg); qo = fmaf(pb.y, hp.x, qo);
            pa = __builtin_amdgcn_cvt_pk_f32_fp8(wq.y, false);
            pb = __builtin_amdgcn_cvt_pk_f32_fp8(wq.y, true);
            qi = fmaf(pa.x, hp.y, qi); qf = fmaf(pa.y, hp.y, qf);
            qg = fmaf(pb.x, hp.y, qg); qo = fmaf(pb.y, hp.y, qo);
            pa = __builtin_amdgcn_cvt_pk_f32_fp8(wq.z, false);
            pb = __builtin_amdgcn_cvt_pk_f32_fp8(wq.z, true);
            qi = fmaf(pa.x, hp.z, qi); qf = fmaf(pa.y, hp.z, qf);
            qg = fmaf(pb.x, hp.z, qg); qo = fmaf(pb.y, hp.z, qo);
            pa = __builtin_amdgcn_cvt_pk_f32_fp8(wq.w, false);
            pb = __builtin_amdgcn_cvt_pk_f32_fp8(wq.w, true);
            qi = fmaf(pa.x, hp.w, qi); qf = fmaf(pa.y, hp.w, qf);
            qg = fmaf(pb.x, hp.w, qg); qo = fmaf(pb.y, hp.w, qo);
        }
        if (half) { part[j][0] = qi; part[j][1] = qf; part[j][2] = qg; part[j][3] = qo; }
        __syncthreads();
        if (half == 0) {
            float4 pr = *(const float4*)&part[j][0];
            ai = fmaf(sc.x, qi + pr.x, ai);
            af = fmaf(sc.y, qf + pr.y, af);
            ag = fmaf(sc.z, qg + pr.z, ag);
            ao = fmaf(sc.w, qo + pr.w, ao);
            cellc = sigf(af)*cellc + sigf(ai)*tanhf(ag);
            float h0 = sigf(ao)*tanhf(cellc);
            hs[j] = h0;
            if (rep == 0) hall[(size_t)(t*64 + pos)*512 + dir*256 + j] = h0;
        }
        __syncthreads();
    }
}

// ---------------------------------------------------------------- uv + p1 + p2 fused
__global__ __launch_bounds__(256) void post_lstm(const float* __restrict__ hall,
                                                 const float* __restrict__ Ws,
                                                 float* __restrict__ u, float* __restrict__ v,
                                                 const float* __restrict__ W1, const float* __restrict__ b1,
                                                 const float* __restrict__ W2, const float* __restrict__ b2,
                                                 float* __restrict__ p1, float* __restrict__ p2) {
    if (blockIdx.x < 512) {
        int bi = blockIdx.x;
        int i  = bi & 63;
        int tid = threadIdx.x;
        float pu = 0.0f, pv = 0.0f;
        for (int q = tid; q < 1536; q += 256) {
            int seg = q >> 9, kk = q & 511;
            float tv = 0.0f;
            if (seg == 0)       tv = hall[(size_t)bi*512 + kk];
            else if (seg == 1)  { if (i > 0)  tv = hall[(size_t)(bi-1)*512 + kk]; }
            else                { if (i < 63) tv = hall[(size_t)(bi+1)*512 + kk]; }
            pu = fmaf(tv, Ws[q],        pu);
            pv = fmaf(tv, Ws[1536 + q], pv);
        }
        for (int off = 32; off; off >>= 1) { pu += __shfl_xor(pu, off); pv += __shfl_xor(pv, off); }
        __shared__ float ru[4], rv[4];
        int wv = tid >> 6, lane = tid & 63;
        if (lane == 0) { ru[wv] = pu; rv[wv] = pv; }
        __syncthreads();
        if (tid == 0) { u[bi] = ru[0]+ru[1]+ru[2]+ru[3]; v[bi] = rv[0]+rv[1]+rv[2]+rv[3]; }
    } else {
        int gb = blockIdx.x - 512;         // 0..127
        int sel = gb >> 6; gb &= 63;       // 64 tiles per matrix: 16 row x 4 col
        gemm32_body(hall, sel ? W2 : W1, sel ? b2 : b1, sel ? p2 : p1,
                    128, 512, gb >> 2, gb & 3);
    }
}

// ---------------------------------------------------------------- Eisner + fused S-GEMM + finalize
// 512 threads/block; 256 blocks = 32 replicas x 8 batches (replica 0 commits).
// LINEAR-DOMAIN DP (round 13, best measured): tables store E = 2^(L - 2*width);
// LSE-of-sums = dot products; fmax/oct_max/exp2/log2 and range masks all
// vanish (out-of-range k always multiplies a zero slot). Seeds T1[d][d]=1,
// T2[d][d-1]=1. logZ = (log2(T1[0][63]) + 126)*ln2.
// Growth log2(3+2*sqrt(2)) ~ 2.54 < 4 -> no fp32 overflow; values in
// ~[2^-15, 2^5] -> no underflow.
// Session ledger (do not re-add): reg-mirror (r8, not LDS-bound); 1024-thr
// 16-lane (r5, issue growth); fused grid-barrier (r14/r15, ~30us/barrier >
// launch gap). Phase A k4 loop: unroll 2 pragma is load-bearing -- full
// unroll spilled 174 MB scratch (r1-2).
__global__ __launch_bounds__(512, 2) void eisner_final(const float* __restrict__ u,
                                                    const float* __restrict__ v,
                                                    const float* __restrict__ bs,
                                                    const float* __restrict__ p1,
                                                    const float* __restrict__ p2,
                                                    const float* __restrict__ prior,
                                                    const int* __restrict__ heads,
                                                    float* __restrict__ out) {
    int b   = blockIdx.x & 7;
    int rep = blockIdx.x >> 3;
    __shared__ __align__(16) float SMEM[3*64*TSTRIDE + 64];   // DP tables / stage / Sl (time-shared)
    __shared__ float su[64], sv[64], lseSb[64], sBest[1];
    float* T1 = &SMEM[0];
    float* T2 = &SMEM[64*TSTRIDE];
    float* T3 = &SMEM[2*64*TSTRIDE];
    int tid = threadIdx.x;
    float bsv = bs[0];
    if (tid < 64) {
        su[tid] = u[b*64 + tid];
        sv[tid] = v[b*64 + tid];
    }
    // ---- Phase A: S = p1[b] @ p2[b]^T (64x64x128), two K-halves through LDS
    const float4* g1 = (const float4*)(p1 + (size_t)b*8192);
    const float4* g2 = (const float4*)(p2 + (size_t)b*8192);
    float4* s1p = (float4*)SMEM;                   // 64 rows x 17 float4 (stride 68 floats)
    float4* s2p = (float4*)(SMEM + 64*TSTRIDE);
    int r   = tid >> 3;                            // output row / span index
    int sub = tid & 7;
    float acc[8];                                  // acc[q] = S[r][sub + 8q]
    #pragma unroll
    for (int q = 0; q < 8; ++q) acc[q] = 0.0f;
    for (int p = 0; p < 2; ++p) {
        #pragma unroll
        for (int f0 = 0; f0 < 4; ++f0) {
            int f = f0*512 + tid;
            int half = f >> 10;                    // 0: p1, 1: p2
            int ff = f & 1023;
            int row = ff >> 4, c4 = ff & 15;
            float4 vv = (half ? g2 : g1)[row*32 + (p<<4) + c4];
            (half ? s2p : s1p)[row*17 + c4] = vv;
        }
        __syncthreads();
        #pragma unroll 2
        for (int k4 = 0; k4 < 16; ++k4) {
            float4 a = s1p[r*17 + k4];
            #pragma unroll
            for (int q = 0; q < 8; ++q) {
                float4 bv = s2p[(sub + (q<<3))*17 + k4];
                acc[q] = fmaf(a.x, bv.x, acc[q]);
                acc[q] = fmaf(a.y, bv.y, acc[q]);
                acc[q] = fmaf(a.z, bv.z, acc[q]);
                acc[q] = fmaf(a.w, bv.w, acc[q]);
            }
        }
        __syncthreads();
    }
    // row-LSE of S straight from registers (8 lanes own a row)
    float pm = acc[0];
    #pragma unroll
    for (int q = 1; q < 8; ++q) pm = fmaxf(pm, acc[q]);
    pm = oct_max(pm);
    float ps = 0.0f;
    #pragma unroll
    for (int q = 0; q < 8; ++q) ps += exp2f((acc[q] - pm) * L2E);
    ps = oct_sum(ps);
    if (sub == 0) lseSb[r] = pm + log2f(ps) * LN2;
    // dump S into recycled stage LDS (stride 66)
    float* Sl = SMEM;
    #pragma unroll
    for (int q = 0; q < 8; ++q) Sl[r*66 + sub + (q<<3)] = acc[q];
    __syncthreads();
    // gold-arc score (wave 0 only), before the DP recycles Sl's LDS
    if (tid < 64) {
        int m = tid;
        float gv = -INFINITY;
        if (m >= 1) {
            int hd = heads[b*64 + m];
            gv = su[hd] + sv[m] + bsv + (Sl[hd*66 + m] - lseSb[hd])
               + prior[(size_t)(b*64 + hd)*64 + m] * (1.0f/64.0f);
        }
        float mm = gv;
        for (int off = 32; off; off >>= 1) mm = fmaxf(mm, __shfl_xor(mm, off));
        float se = (m >= 1) ? exp2f((gv - mm) * L2E) : 0.0f;
        for (int off = 32; off; off >>= 1) se += __shfl_xor(se, off);
        if (m == 0) sBest[0] = mm + log2f(se) * LN2;
    }
    __syncthreads();
    // ---- Phase B: zero tables (zero = "no entry" in linear domain) + seeds
    for (int q = tid; q < 3*64*TSTRIDE; q += 512) SMEM[q] = 0.0f;
    __syncthreads();
    if (tid < 64) {
        T1[tid*TSTRIDE + tid] = 1.0f;              // C_r[d][d] = 0 nats
        if (tid >= 1) T2[tid*TSTRIDE + tid-1] = 1.0f;  // C_l[d][d] (shifted slot)
    }
    __syncthreads();
    int i = r;
    int k0 = i & ~3;
    float sui_b = su[i] + bsv;
    float svi_b = sv[i] + bsv;
    const float* t1i = &T1[i*TSTRIDE];
    const float* t2i = &T2[i*TSTRIDE];
    const float* t3i = &T3[i*TSTRIDE];
    for (int w = 1; w < 64; ++w) {
        int ns = 64 - w;
        if (i < ns) {
            int j = i + w;
            const float* t1j = &T1[j*TSTRIDE];
            const float* t2j = &T2[j*TSTRIDE];
            const float* t3j = &T3[j*TSTRIDE];
            float eDr = exp2f((sui_b + sv[j]) * L2E);
            float eDl = exp2f((su[j] + svi_b) * L2E);
            float s1 = 0.0f, sr = 0.0f, sl = 0.0f;
            #pragma unroll
            for (int t = 0; t < 2; ++t) {
                int k = k0 + ((t << 3) + sub) * 4;
                if (k < j) {
                    float4 a1  = *(const float4*)&t1i[k];
                    float4 b1  = *(const float4*)&t2j[k];
                    float4 a2  = *(const float4*)&t3i[k];
                    float4 b2v = *(const float4*)&t1j[k];
                    float4 a3  = *(const float4*)&t2i[k];
                    float4 b3  = *(const float4*)&t3j[k];
                    #pragma unroll
                    for (int c = 0; c < 4; ++c) {
                        s1 = fmaf(((const float*)&a1)[c], ((const float*)&b1)[c],  s1);
                        sr = fmaf(((const float*)&a2)[c], ((const float*)&b2v)[c], sr);
                        sl = fmaf(((const float*)&a3)[c], ((const float*)&b3)[c],  sl);
                    }
                }
            }
            s1 = oct_sum(s1);
            sr = oct_sum(sr);
            sl = oct_sum(sl);
            if (sub == 0) {
                float Ir = 0.25f * s1 * eDr;       // va width-sum = w-1 -> 2^-2
                float Il = 0.25f * s1 * eDl;
                float Cr = sr + Ir;
                float Cl = sl + Il;
                T3[i*TSTRIDE + j] = Ir;
                T1[i*TSTRIDE + j] = Cr;
                T1[j*TSTRIDE + i] = Cr;
                T3[j*TSTRIDE + i] = Il;
                T2[i*TSTRIDE + j] = Cl;
                if (i >= 1) T2[j*TSTRIDE + i-1] = Cl;
            }
        }
        __syncthreads();
    }
    if (rep == 0 && tid == 0) {
        float logZv = (log2f(T1[0*TSTRIDE + 63]) + 126.0f) * LN2;
        atomicAdd(out, -(sBest[0] - logZv) * 0.125f);
    }
}

// ---------------------------------------------------------------- launch
extern "C" void kernel_launch(void* const* d_in, const int* in_sizes, int n_in,
                              void* d_out, int out_size, void* d_ws, size_t ws_size,
                              hipStream_t stream) {
    const int*   sents = (const int*)  d_in[0];
    const float* mask  = (const float*)d_in[1];
    const float* prior = (const float*)d_in[2];
    const int*   heads = (const int*)  d_in[3];
    const float* emb   = (const float*)d_in[4];
    const float* Wih_f = (const float*)d_in[5];
    const float* Whh_f = (const float*)d_in[6];
    const float* bih_f = (const float*)d_in[7];
    const float* bhh_f = (const float*)d_in[8];
    const float* Wih_b = (const float*)d_in[9];
    const float* Whh_b = (const float*)d_in[10];
    const float* bih_b = (const float*)d_in[11];
    const float* bhh_b = (const float*)d_in[12];
    const float* W1    = (const float*)d_in[13];
    const float* b1    = (const float*)d_in[14];
    const float* W2    = (const float*)d_in[15];
    const float* b2    = (const float*)d_in[16];
    const float* Ws    = (const float*)d_in[17];
    const float* bs    = (const float*)d_in[18];
    float* out = (float*)d_out;

    char* w = (char*)d_ws;
    float* embeds = (float*)(w + 0);                 // 512 KB
    float* gxf    = (float*)(w + 524288);            // 2 MB
    float* gxb    = (float*)(w + 2621440);           // 2 MB
    uint4* qWf    = (uint4*)(w + 4718592);           // 256 KB
    uint4* qWb    = (uint4*)(w + 4980736);           // 256 KB
    float* scf    = (float*)(w + 5242880);           // 4 KB
    float* scb    = (float*)(w + 5246976);           // 4 KB
    float* biasf  = (float*)(w + 5767168);           // 4 KB
    float* biasb  = (float*)(w + 5771264);           // 4 KB
    float* hall   = (float*)(w + 5775360);           // 1 MB
    float* uArr   = (float*)(w + 6823936);
    float* vArr   = (float*)(w + 6825984);
    float* p1     = (float*)(w + 6828032);
    float* p2     = (float*)(w + 7090176);

    prep_all<<<640, 256, 0, stream>>>(Whh_f, Whh_b, bih_f, bhh_f, bih_b, bhh_b,
                                      qWf, qWb, scf, scb, biasf, biasb,
                                      sents, mask, emb, embeds, out);
    gemm_ih<<<dim3(8,16,2), 256, 0, stream>>>(embeds, Wih_f, Wih_b, biasf, biasb, gxf, gxb);
    lstm_rec<<<256, 512, 0, stream>>>(gxf, gxb, qWf, qWb, scf, scb, hall);
    post_lstm<<<640, 256, 0, stream>>>(hall, Ws, uArr, vArr, W1, b1, W2, b2, p1, p2);
    eisner_final<<<256, 512, 0, stream>>>(uArr, vArr, bs, p1, p2, prior, heads, out);
    (void)in_sizes; (void)n_in; (void)out_size; (void)ws_size;
}